// Round 2
// baseline (730.095 us; speedup 1.0000x reference)
//
#include <hip/hip_runtime.h>

#define D 64

__device__ __forceinline__ float bfbits2f(unsigned short b) {
    union { unsigned int u; float f; } c;
    c.u = ((unsigned int)b) << 16;
    return c.f;
}

__device__ __forceinline__ unsigned short f2bfbits(float f) {
    union { float f; unsigned int u; } c;
    c.f = f;
    unsigned int u = c.u;
    unsigned int lsb = (u >> 16) & 1u;
    u += 0x7fffu + lsb;           // round-to-nearest-even
    return (unsigned short)(u >> 16);
}

// load element i from p, which is fp32 if isf32 else bf16
__device__ __forceinline__ float ldmix(const void* p, size_t i, int isf32) {
    return isf32 ? ((const float*)p)[i] : bfbits2f(((const unsigned short*)p)[i]);
}

// ---- dtype sniff -----------------------------------------------------------
// Read first 256 ushorts of W1 as bf16. If data is actually fp32, the low
// halves of floats decode to huge/non-finite bf16 values with overwhelming
// probability. flag=1 => inputs are fp32.
__global__ void sniff_kernel(const unsigned short* __restrict__ W, int* __restrict__ flag) {
    int t = threadIdx.x;
    bool bad = false;
    for (int i = t; i < 256; i += 64) {
        float v = bfbits2f(W[i]);
        if (!(v == v) || fabsf(v) > 1e4f) bad = true;
    }
    unsigned long long m = __ballot(bad);
    if (t == 0) *flag = (m != 0ull) ? 1 : 0;
}

// ---- param conversion ------------------------------------------------------
// P layout (floats): W1@0, W2@4096, W3@8192, b1@12288, b2@12352, b3@12416,
//                    g@12480, be@12544, pa@12608
#define OW1 0
#define OW2 4096
#define OW3 8192
#define OB1 12288
#define OB2 12352
#define OB3 12416
#define OG  12480
#define OBE 12544
#define OPA 12608

__global__ void cvt_params_kernel(const void* W1, const void* b1, const void* W2, const void* b2,
                                  const void* W3, const void* b3, const void* pa, const void* g,
                                  const void* be, const int* __restrict__ flag,
                                  float* __restrict__ P) {
    int isf = *flag;
    int t = threadIdx.x;                 // one block of 256
    for (int i = t; i < D * D; i += 256) {
        P[OW1 + i] = ldmix(W1, i, isf);
        P[OW2 + i] = ldmix(W2, i, isf);
        P[OW3 + i] = ldmix(W3, i, isf);
    }
    if (t < D) {
        P[OB1 + t] = ldmix(b1, t, isf);
        P[OB2 + t] = ldmix(b2, t, isf);
        P[OB3 + t] = ldmix(b3, t, isf);
        P[OG  + t] = ldmix(g,  t, isf);
        P[OBE + t] = ldmix(be, t, isf);
    }
    if (t == 0) P[OPA] = ldmix(pa, 0, isf);
}

// ---- CSR build -------------------------------------------------------------

__global__ void count_kernel(const int* __restrict__ dst, int* __restrict__ cnt, int E) {
    int e = blockIdx.x * blockDim.x + threadIdx.x;
    if (e < E) atomicAdd(&cnt[dst[e]], 1);
}

// single-block exclusive scan over cnt -> row_off/cursor; also dinv = rsqrt(cnt+1)
__global__ void scan_kernel(const int* __restrict__ cnt, int* __restrict__ row_off,
                            int* __restrict__ cursor, float* __restrict__ dinv, int n) {
    __shared__ int tile[1024];
    int t = threadIdx.x;
    int carry = 0;
    for (int base = 0; base < n; base += 1024) {
        int i = base + t;
        int v = (i < n) ? cnt[i] : 0;
        tile[t] = v;
        __syncthreads();
        for (int off = 1; off < 1024; off <<= 1) {
            int add = (t >= off) ? tile[t - off] : 0;
            __syncthreads();
            tile[t] += add;
            __syncthreads();
        }
        int excl = carry + tile[t] - v;
        if (i < n) {
            row_off[i] = excl;
            cursor[i]  = excl;
            dinv[i]    = rsqrtf((float)(v + 1));
        }
        carry += tile[1023];
        __syncthreads();   // protect tile[] before next-iteration overwrite
    }
    if (t == 0) row_off[n] = carry;
}

__global__ void fill_kernel(const int* __restrict__ src, const int* __restrict__ dst,
                            int* __restrict__ cursor, int* __restrict__ col, int E) {
    int e = blockIdx.x * blockDim.x + threadIdx.x;
    if (e < E) {
        int d = dst[e];
        int pos = atomicAdd(&cursor[d], 1);
        col[pos] = src[e];
    }
}

// ---- feature kernels -------------------------------------------------------

// Xs[i][j] = dinv[i] * cvt(X[i][j])   (layer-1 input prescale, fp32 out)
__global__ void prescale_kernel(const void* __restrict__ X, const float* __restrict__ dinv,
                                const int* __restrict__ flag, float* __restrict__ Xs, int n) {
    int isf = *flag;
    int gid  = blockIdx.x * blockDim.x + threadIdx.x;
    int node = gid >> 6;
    if (node >= n) return;
    Xs[gid] = dinv[node] * ldmix(X, (size_t)gid, isf);
}

// Y[d] = dinv[d] * ( Xs[d] + sum_{s in CSR[d]} Xs[s] )
__global__ void agg_kernel(const float* __restrict__ Xs,
                           const int* __restrict__ row_off, const int* __restrict__ col,
                           const float* __restrict__ dinv, float* __restrict__ Y, int n) {
    int gid  = blockIdx.x * blockDim.x + threadIdx.x;
    int node = gid >> 6, lane = gid & 63;
    if (node >= n) return;
    float acc = Xs[(size_t)node * D + lane];             // self-loop term (prescaled)
    int beg = row_off[node], end = row_off[node + 1];
    for (int chunk = beg; chunk < end; chunk += 64) {
        int m = end - chunk; if (m > 64) m = 64;
        int idx = (lane < m) ? col[chunk + lane] : 0;    // batch-load indices via lanes
        for (int i = 0; i < m; ++i) {
            int s = __shfl(idx, i, 64);                  // broadcast
            acc += Xs[(size_t)s * D + lane];             // 256B coalesced row
        }
    }
    Y[(size_t)node * D + lane] = dinv[node] * acc;
}

// Xout[n] = dinv[n] * prelu( Y[n] @ W + b )   (feeds next layer, prescaled)
__global__ void gemm_kernel(const float* __restrict__ Y, const float* __restrict__ W,
                            const float* __restrict__ b, const float* __restrict__ pa,
                            const float* __restrict__ dinv, float* __restrict__ Xout, int n) {
    __shared__ float Wl[D * D];
    int t = threadIdx.x;
    for (int i = t; i < D * D; i += 256) Wl[i] = W[i];
    __syncthreads();
    int node = blockIdx.x * 4 + (t >> 6);
    int lane = t & 63;
    if (node >= n) return;
    float xr  = Y[(size_t)node * D + lane];
    float acc = 0.f;
#pragma unroll
    for (int k = 0; k < D; ++k) {
        float xv = __shfl(xr, k, 64);
        acc = fmaf(xv, Wl[k * D + lane], acc);
    }
    acc += b[lane];
    float a = pa[0];
    acc = (acc >= 0.f) ? acc : a * acc;
    acc *= dinv[node];                           // prescale for next layer's aggregation
    Xout[(size_t)node * D + lane] = acc;
}

// layer 3: out[n] = LayerNorm( Y[n] @ W + b ) * gamma + beta, write fp32 or bf16
__global__ void gemm_ln_kernel(const float* __restrict__ Y, const float* __restrict__ W,
                               const float* __restrict__ b,
                               const float* __restrict__ g, const float* __restrict__ be,
                               const int* __restrict__ flag, void* __restrict__ out, int n) {
    __shared__ float Wl[D * D];
    int t = threadIdx.x;
    for (int i = t; i < D * D; i += 256) Wl[i] = W[i];
    __syncthreads();
    int node = blockIdx.x * 4 + (t >> 6);
    int lane = t & 63;
    if (node >= n) return;
    float xr  = Y[(size_t)node * D + lane];
    float acc = 0.f;
#pragma unroll
    for (int k = 0; k < D; ++k) {
        float xv = __shfl(xr, k, 64);
        acc = fmaf(xv, Wl[k * D + lane], acc);
    }
    acc += b[lane];
    // LayerNorm across the 64 lanes (one node per wave)
    float s = acc;
#pragma unroll
    for (int off = 32; off > 0; off >>= 1) s += __shfl_xor(s, off, 64);
    float mu  = s * (1.f / 64.f);
    float dfe = acc - mu;
    float v   = dfe * dfe;
#pragma unroll
    for (int off = 32; off > 0; off >>= 1) v += __shfl_xor(v, off, 64);
    float var = v * (1.f / 64.f);
    float r   = rsqrtf(var + 1e-5f);
    float o   = dfe * r * g[lane] + be[lane];
    size_t oi = (size_t)node * D + lane;
    if (*flag) ((float*)out)[oi] = o;
    else       ((unsigned short*)out)[oi] = f2bfbits(o);
}

// ---- driver ----------------------------------------------------------------

extern "C" void kernel_launch(void* const* d_in, const int* in_sizes, int n_in,
                              void* d_out, int out_size, void* d_ws, size_t ws_size,
                              hipStream_t stream) {
    const void* X   = d_in[0];
    const void* W1  = d_in[1];
    const void* b1  = d_in[2];
    const void* W2  = d_in[3];
    const void* b2  = d_in[4];
    const void* W3  = d_in[5];
    const void* b3  = d_in[6];
    const void* pa  = d_in[7];
    const void* g   = d_in[8];
    const void* be  = d_in[9];
    const int*  ei  = (const int*)d_in[10];

    int N = in_sizes[0] / D;
    int E = in_sizes[10] / 2;
    const int* src = ei;
    const int* dst = ei + E;

    char* p = (char*)d_ws;
    auto alloc = [&](size_t bytes) { void* q = (void*)p; p += (bytes + 255) & ~(size_t)255; return q; };
    int*   flag    = (int*)alloc(4);
    int*   cnt     = (int*)alloc((size_t)N * 4);
    int*   row_off = (int*)alloc((size_t)(N + 1) * 4);
    int*   cursor  = (int*)alloc((size_t)N * 4);
    float* dinv    = (float*)alloc((size_t)N * 4);
    int*   col     = (int*)alloc((size_t)E * 4);
    float* P       = (float*)alloc((size_t)(OPA + 1) * 4);
    float* Yf      = (float*)alloc((size_t)N * D * 4);
    float* Xs      = (float*)alloc((size_t)N * D * 4);
    float* Xs2     = (float*)alloc((size_t)N * D * 4);
    (void)ws_size; (void)n_in; (void)out_size;

    hipMemsetAsync(cnt, 0, (size_t)N * 4, stream);

    sniff_kernel<<<1, 64, 0, stream>>>((const unsigned short*)W1, flag);
    cvt_params_kernel<<<1, 256, 0, stream>>>(W1, b1, W2, b2, W3, b3, pa, g, be, flag, P);

    int eb = (E + 255) / 256;
    count_kernel<<<eb, 256, 0, stream>>>(dst, cnt, E);
    scan_kernel<<<1, 1024, 0, stream>>>(cnt, row_off, cursor, dinv, N);
    fill_kernel<<<eb, 256, 0, stream>>>(src, dst, cursor, col, E);

    int nwb = (N * D + 255) / 256;   // one wave per node
    int ngb = (N + 3) / 4;           // gemm: 4 nodes per 256-thread block

    prescale_kernel<<<nwb, 256, 0, stream>>>(X, dinv, flag, Xs, N);

    // layer 1
    agg_kernel <<<nwb, 256, 0, stream>>>(Xs, row_off, col, dinv, Yf, N);
    gemm_kernel<<<ngb, 256, 0, stream>>>(Yf, P + OW1, P + OB1, P + OPA, dinv, Xs2, N);
    // layer 2
    agg_kernel <<<nwb, 256, 0, stream>>>(Xs2, row_off, col, dinv, Yf, N);
    gemm_kernel<<<ngb, 256, 0, stream>>>(Yf, P + OW2, P + OB2, P + OPA, dinv, Xs, N);
    // layer 3
    agg_kernel <<<nwb, 256, 0, stream>>>(Xs, row_off, col, dinv, Yf, N);
    gemm_ln_kernel<<<ngb, 256, 0, stream>>>(Yf, P + OW3, P + OB3, P + OG, P + OBE, flag, d_out, N);
}

// Round 4
// 495.408 us; speedup vs baseline: 1.4737x; 1.4737x over previous
//
#include <hip/hip_runtime.h>

#define D 64

__device__ __forceinline__ float bfbits2f(unsigned short b) {
    union { unsigned int u; float f; } c;
    c.u = ((unsigned int)b) << 16;
    return c.f;
}

__device__ __forceinline__ unsigned short f2bfbits(float f) {
    union { float f; unsigned int u; } c;
    c.f = f;
    unsigned int u = c.u;
    unsigned int lsb = (u >> 16) & 1u;
    u += 0x7fffu + lsb;           // round-to-nearest-even
    return (unsigned short)(u >> 16);
}

// load element i from p, which is fp32 if isf32 else bf16
__device__ __forceinline__ float ldmix(const void* p, size_t i, int isf32) {
    return isf32 ? ((const float*)p)[i] : bfbits2f(((const unsigned short*)p)[i]);
}

// ---- dtype sniff -----------------------------------------------------------
__global__ void sniff_kernel(const unsigned short* __restrict__ W, int* __restrict__ flag) {
    int t = threadIdx.x;
    bool bad = false;
    for (int i = t; i < 256; i += 64) {
        float v = bfbits2f(W[i]);
        if (!(v == v) || fabsf(v) > 1e4f) bad = true;
    }
    unsigned long long m = __ballot(bad);
    if (t == 0) *flag = (m != 0ull) ? 1 : 0;
}

// ---- param conversion ------------------------------------------------------
// P layout (floats): W1@0, W2@4096, W3@8192, b1@12288, b2@12352, b3@12416,
//                    g@12480, be@12544, pa@12608
#define OW1 0
#define OW2 4096
#define OW3 8192
#define OB1 12288
#define OB2 12352
#define OB3 12416
#define OG  12480
#define OBE 12544
#define OPA 12608

__global__ void cvt_params_kernel(const void* W1, const void* b1, const void* W2, const void* b2,
                                  const void* W3, const void* b3, const void* pa, const void* g,
                                  const void* be, const int* __restrict__ flag,
                                  float* __restrict__ P) {
    int isf = *flag;
    int t = threadIdx.x;                 // one block of 256
    for (int i = t; i < D * D; i += 256) {
        P[OW1 + i] = ldmix(W1, i, isf);
        P[OW2 + i] = ldmix(W2, i, isf);
        P[OW3 + i] = ldmix(W3, i, isf);
    }
    if (t < D) {
        P[OB1 + t] = ldmix(b1, t, isf);
        P[OB2 + t] = ldmix(b2, t, isf);
        P[OB3 + t] = ldmix(b3, t, isf);
        P[OG  + t] = ldmix(g,  t, isf);
        P[OBE + t] = ldmix(be, t, isf);
    }
    if (t == 0) P[OPA] = ldmix(pa, 0, isf);
}

// ---- CSR build (scan-free: segment bases via block atomics) ----------------

__global__ void count_kernel(const int* __restrict__ dst, int* __restrict__ cnt, int E) {
    int e = blockIdx.x * blockDim.x + threadIdx.x;
    if (e < E) atomicAdd(&cnt[dst[e]], 1);
}

// row_beg[i] = segment base (arbitrary global order); cursor=copy; dinv=rsqrt(cnt+1)
__global__ void offsets_kernel(const int* __restrict__ cnt, int* __restrict__ row_beg,
                               int* __restrict__ cursor, float* __restrict__ dinv,
                               int* __restrict__ total, int n) {
    int t    = threadIdx.x;
    int lane = t & 63, wid = t >> 6;
    int i = blockIdx.x * 256 + t;
    int v = (i < n) ? cnt[i] : 0;
    // wave inclusive scan
    int incl = v;
#pragma unroll
    for (int off = 1; off < 64; off <<= 1) {
        int u = __shfl_up(incl, off, 64);
        if (lane >= off) incl += u;
    }
    __shared__ int wsum[4];
    __shared__ int base;
    if (lane == 63) wsum[wid] = incl;
    __syncthreads();
    if (t == 0) {
        int s = 0;
#pragma unroll
        for (int j = 0; j < 4; ++j) { int w = wsum[j]; wsum[j] = s; s += w; }
        base = atomicAdd(total, s);
    }
    __syncthreads();
    if (i < n) {
        int beg = base + wsum[wid] + incl - v;
        row_beg[i] = beg;
        cursor[i]  = beg;
        dinv[i]    = rsqrtf((float)(v + 1));
    }
}

__global__ void fill_kernel(const int* __restrict__ src, const int* __restrict__ dst,
                            int* __restrict__ cursor, int* __restrict__ col, int E) {
    int e = blockIdx.x * blockDim.x + threadIdx.x;
    if (e < E) {
        int d = dst[e];
        int pos = atomicAdd(&cursor[d], 1);
        col[pos] = src[e];
    }
}

// ---- feature kernels -------------------------------------------------------

// Xs[i][j] = bf16( dinv[i] * cvt(X[i][j]) )   (layer-1 input prescale)
__global__ void prescale_kernel(const void* __restrict__ X, const float* __restrict__ dinv,
                                const int* __restrict__ flag, unsigned short* __restrict__ Xs, int n) {
    int isf = *flag;
    int gid  = blockIdx.x * blockDim.x + threadIdx.x;
    int node = gid >> 6;
    if (node >= n) return;
    Xs[gid] = f2bfbits(dinv[node] * ldmix(X, (size_t)gid, isf));
}

// shared gather: acc = dinv[node] * ( Xs[node] + sum_neighbors Xs[s] )   (per lane)
__device__ __forceinline__ float aggregate(const unsigned short* __restrict__ Xs,
                                           const int* __restrict__ row_beg,
                                           const int* __restrict__ cnt,
                                           const int* __restrict__ col,
                                           const float* __restrict__ dinv,
                                           int node, int lane) {
    float a0 = bfbits2f(Xs[(size_t)node * D + lane]);    // self loop
    float a1 = 0.f, a2 = 0.f, a3 = 0.f;
    int beg = row_beg[node], m_tot = cnt[node];
    for (int chunk = 0; chunk < m_tot; chunk += 64) {
        int m = m_tot - chunk; if (m > 64) m = 64;
        int idx = (lane < m) ? col[beg + chunk + lane] : 0;
        int i = 0;
        for (; i + 3 < m; i += 4) {                      // 4 loads in flight
            int s0 = __shfl(idx, i,     64);
            int s1 = __shfl(idx, i + 1, 64);
            int s2 = __shfl(idx, i + 2, 64);
            int s3 = __shfl(idx, i + 3, 64);
            a0 += bfbits2f(Xs[(size_t)s0 * D + lane]);
            a1 += bfbits2f(Xs[(size_t)s1 * D + lane]);
            a2 += bfbits2f(Xs[(size_t)s2 * D + lane]);
            a3 += bfbits2f(Xs[(size_t)s3 * D + lane]);
        }
        for (; i < m; ++i) {
            int s0 = __shfl(idx, i, 64);
            a0 += bfbits2f(Xs[(size_t)s0 * D + lane]);
        }
    }
    return dinv[node] * ((a0 + a1) + (a2 + a3));
}

// fused: Xout[n] = bf16( dinv[n] * prelu( Agg(n) @ W + b ) )
__global__ void agg_gemm_kernel(const unsigned short* __restrict__ Xs,
                                const int* __restrict__ row_beg, const int* __restrict__ cnt,
                                const int* __restrict__ col, const float* __restrict__ dinv,
                                const float* __restrict__ W, const float* __restrict__ b,
                                const float* __restrict__ pa,
                                unsigned short* __restrict__ Xout, int n) {
    __shared__ float Wl[D * D];
    int t = threadIdx.x;
    for (int i = t; i < D * D; i += 256) Wl[i] = W[i];
    __syncthreads();
    int node = blockIdx.x * 4 + (t >> 6);
    int lane = t & 63;
    if (node >= n) return;
    float xr = aggregate(Xs, row_beg, cnt, col, dinv, node, lane);
    float acc = 0.f;
#pragma unroll
    for (int k = 0; k < D; ++k) {
        float xv = __shfl(xr, k, 64);
        acc = fmaf(xv, Wl[k * D + lane], acc);
    }
    acc += b[lane];
    float a = pa[0];
    acc = (acc >= 0.f) ? acc : a * acc;
    acc *= dinv[node];                            // prescale for next layer's aggregation
    Xout[(size_t)node * D + lane] = f2bfbits(acc);
}

// fused layer 3: out[n] = LayerNorm( Agg(n) @ W + b ) * gamma + beta
__global__ void agg_gemm_ln_kernel(const unsigned short* __restrict__ Xs,
                                   const int* __restrict__ row_beg, const int* __restrict__ cnt,
                                   const int* __restrict__ col, const float* __restrict__ dinv,
                                   const float* __restrict__ W, const float* __restrict__ b,
                                   const float* __restrict__ g, const float* __restrict__ be,
                                   const int* __restrict__ flag, void* __restrict__ out, int n) {
    __shared__ float Wl[D * D];
    int t = threadIdx.x;
    for (int i = t; i < D * D; i += 256) Wl[i] = W[i];
    __syncthreads();
    int node = blockIdx.x * 4 + (t >> 6);
    int lane = t & 63;
    if (node >= n) return;
    float xr = aggregate(Xs, row_beg, cnt, col, dinv, node, lane);
    float acc = 0.f;
#pragma unroll
    for (int k = 0; k < D; ++k) {
        float xv = __shfl(xr, k, 64);
        acc = fmaf(xv, Wl[k * D + lane], acc);
    }
    acc += b[lane];
    float s = acc;
#pragma unroll
    for (int off = 32; off > 0; off >>= 1) s += __shfl_xor(s, off, 64);
    float mu  = s * (1.f / 64.f);
    float dfe = acc - mu;
    float v   = dfe * dfe;
#pragma unroll
    for (int off = 32; off > 0; off >>= 1) v += __shfl_xor(v, off, 64);
    float var = v * (1.f / 64.f);
    float r   = rsqrtf(var + 1e-5f);
    float o   = dfe * r * g[lane] + be[lane];
    size_t oi = (size_t)node * D + lane;
    if (*flag) ((float*)out)[oi] = o;
    else       ((unsigned short*)out)[oi] = f2bfbits(o);
}

// ---- driver ----------------------------------------------------------------

extern "C" void kernel_launch(void* const* d_in, const int* in_sizes, int n_in,
                              void* d_out, int out_size, void* d_ws, size_t ws_size,
                              hipStream_t stream) {
    const void* X   = d_in[0];
    const void* W1  = d_in[1];
    const void* b1  = d_in[2];
    const void* W2  = d_in[3];
    const void* b2  = d_in[4];
    const void* W3  = d_in[5];
    const void* b3  = d_in[6];
    const void* pa  = d_in[7];
    const void* g   = d_in[8];
    const void* be  = d_in[9];
    const int*  ei  = (const int*)d_in[10];

    int N = in_sizes[0] / D;
    int E = in_sizes[10] / 2;
    const int* src = ei;
    const int* dst = ei + E;

    char* p = (char*)d_ws;
    auto alloc = [&](size_t bytes) { void* q = (void*)p; p += (bytes + 255) & ~(size_t)255; return q; };
    int*            flag    = (int*)alloc(4);
    int*            total   = (int*)alloc(4);
    int*            cnt     = (int*)alloc((size_t)N * 4);
    int*            row_beg = (int*)alloc((size_t)N * 4);
    int*            cursor  = (int*)alloc((size_t)N * 4);
    float*          dinv    = (float*)alloc((size_t)N * 4);
    int*            col     = (int*)alloc((size_t)E * 4);
    float*          P       = (float*)alloc((size_t)(OPA + 1) * 4);
    unsigned short* Xs      = (unsigned short*)alloc((size_t)N * D * 2);
    unsigned short* Xs2     = (unsigned short*)alloc((size_t)N * D * 2);
    (void)ws_size; (void)n_in; (void)out_size;

    (void)hipMemsetAsync(cnt, 0, (size_t)N * 4, stream);
    (void)hipMemsetAsync(total, 0, 4, stream);

    sniff_kernel<<<1, 64, 0, stream>>>((const unsigned short*)W1, flag);
    cvt_params_kernel<<<1, 256, 0, stream>>>(W1, b1, W2, b2, W3, b3, pa, g, be, flag, P);

    int eb = (E + 255) / 256;
    int nb = (N + 255) / 256;
    count_kernel  <<<eb, 256, 0, stream>>>(dst, cnt, E);
    offsets_kernel<<<nb, 256, 0, stream>>>(cnt, row_beg, cursor, dinv, total, N);
    fill_kernel   <<<eb, 256, 0, stream>>>(src, dst, cursor, col, E);

    int nwb = (N * D + 255) / 256;   // one wave per node
    int ngb = (N + 3) / 4;           // 4 nodes per 256-thread block

    prescale_kernel<<<nwb, 256, 0, stream>>>(X, dinv, flag, Xs, N);

    agg_gemm_kernel   <<<ngb, 256, 0, stream>>>(Xs,  row_beg, cnt, col, dinv, P + OW1, P + OB1, P + OPA, Xs2, N);
    agg_gemm_kernel   <<<ngb, 256, 0, stream>>>(Xs2, row_beg, cnt, col, dinv, P + OW2, P + OB2, P + OPA, Xs,  N);
    agg_gemm_ln_kernel<<<ngb, 256, 0, stream>>>(Xs,  row_beg, cnt, col, dinv, P + OW3, P + OB3, P + OG, P + OBE, flag, d_out, N);
}